// Round 10
// baseline (10717.604 us; speedup 1.0000x reference)
//
#include <hip/hip_runtime.h>
#include <hip/hip_fp16.h>
#include <cstdint>
#include <cstddef>

#define EPSF 2.220446049250313e-16f

// Sizes (fixed by the problem)
#define Bn   64
#define TP2n 1024
#define Tn   1023
#define Hn   256
#define H7n  1792
#define Kn   128
#define NEn  131
#define QB   4      // batches per quad (amortize the MALL handshake 4x)

typedef _Float16 f16x2 __attribute__((ext_vector_type(2)));
typedef unsigned uintx4 __attribute__((ext_vector_type(4)));

__device__ __forceinline__ f16x2 u2h(unsigned u) { return __builtin_bit_cast(f16x2, u); }
__device__ __forceinline__ f16x2 f2h(float f)    { return __builtin_bit_cast(f16x2, f); }

__device__ __forceinline__ float fdot2f(f16x2 a, f16x2 b, float c) {
#if __has_builtin(__builtin_amdgcn_fdot2)
  return __builtin_amdgcn_fdot2(a, b, c, false);
#else
  return c + (float)a[0] * (float)b[0] + (float)a[1] * (float)b[1];
#endif
}

__device__ __forceinline__ float sigmf(float x) { return 1.f / (1.f + __expf(-x)); }

__device__ __forceinline__ float tanhfast(float x) {
  float t = __expf(2.f * fabsf(x));        // inf-safe: t=inf -> r=1
  float r = 1.f - 2.f / (t + 1.f);
  return copysignf(r, x);
}

__device__ __forceinline__ float softplusf(float x) {
  return fmaxf(x, 0.f) + log1pf(__expf(-fabsf(x)));
}

// ---------------------------------------------------------------------------
// EW[e][r] = b[r] + sum_k Emb[e][k] * W[r][k]   (input half of W, k<256)
__global__ void k_ew(const float* __restrict__ Emb, const float* __restrict__ W,
                     const float* __restrict__ bvec, float* __restrict__ EW) {
  int e = blockIdx.x;  // 0..130
  __shared__ float es[Hn];
  for (int k = threadIdx.x; k < Hn; k += blockDim.x) es[k] = Emb[e * Hn + k];
  __syncthreads();
  for (int r = threadIdx.x; r < H7n; r += blockDim.x) {
    const float* wr = W + (size_t)r * (2 * Hn);
    float acc = bvec[r];
#pragma unroll 4
    for (int k = 0; k < Hn; ++k) acc += es[k] * wr[k];
    EW[e * H7n + r] = acc;
  }
}

// ---------------------------------------------------------------------------
// Quantize recurrent weights to fp8-e4m3 with per-row scale (s_r = max/448).
// One wave per row. Output word j of row r = bytes (q[4j],q[4j+2],q[4j+1],
// q[4j+3]) so the scan's pair-decode is pure masks. sc[r] = s_r * 256.
__global__ __launch_bounds__(64) void k_wq(const float* __restrict__ W,
                                           unsigned* __restrict__ wq,
                                           float* __restrict__ sc) {
  const int r = blockIdx.x;           // 0..1791
  const int j = threadIdx.x;          // 0..63
  const float* wr = W + (size_t)r * 512 + 256;
  float4 wv = *reinterpret_cast<const float4*>(wr + 4 * j);
  float m = fmaxf(fmaxf(fabsf(wv.x), fabsf(wv.y)),
                  fmaxf(fabsf(wv.z), fabsf(wv.w)));
#pragma unroll
  for (int off = 32; off; off >>= 1) m = fmaxf(m, __shfl_xor(m, off));
  float inv_s = (m > 0.f) ? 448.f / m : 0.f;
  float v[4] = {wv.x, wv.y, wv.z, wv.w};
  unsigned b[4];
#pragma unroll
  for (int q = 0; q < 4; ++q) {
    float ay = fabsf(v[q]) * inv_s;     // in [0, 448]
    unsigned byte;
    if (ay < 0.015625f) {               // < 2^-6: denorm m*2^-9 (RNE, rollover ok)
      byte = (unsigned)(int)rintf(ay * 512.f);
    } else {                            // normal: rebias to 7, RNE to 3-bit mantissa
      unsigned ub = __builtin_bit_cast(unsigned, ay);
      unsigned E  = (ub >> 23) & 255u;
      unsigned vv = ((E - 120u) << 23) | (ub & 0x7fffffu);
      byte = (vv + 0x7ffffu + ((vv >> 20) & 1u)) >> 20;
      if (byte > 0x7eu) byte = 0x7eu;   // clamp at 448
    }
    if (v[q] < 0.f) byte |= 0x80u;
    b[q] = byte;
  }
  wq[(size_t)r * 64 + j] = b[0] | (b[2] << 8) | (b[1] << 16) | (b[3] << 24);
  if (j == 0) sc[r] = (m / 448.f) * 256.f;
}

// ---------------------------------------------------------------------------
__global__ void k_init(float* __restrict__ acc, int* __restrict__ flags) {
  int i = threadIdx.x;  // 1024 threads
  if (i < 192) acc[i] = 0.f;  // lam_acc[64], mask_acc[64], loglik_sum[64]
  flags[i] = 0;               // 64 batches x 16 ints (64B padded)
}

// ---------------------------------------------------------------------------
// Sequential CT-LSTM scan: 16 quads x 4 roles = 64 blocks; each quad runs
// FOUR batches in lockstep. Round-9 post-mortem: the per-step cost is the
// agent-scope (MALL) exchange chain (z stores -> flag -> poll -> z loads,
// ~13K cycles), NOT weight streaming (fp16->fp8 changed nothing; WRITE_SIZE
// showed 469MB of zx traffic hitting MALL). Batching 4 recurrences per quad
// pays that chain ONCE per 4 batch-steps: the 4 exchanges launch together
// and 16 poller lanes spin concurrently. Weights are decoded once and dotted
// against 4 h vectors (LDS layout hh[k2][m]: one b128 broadcast = one k-pair
// x all 4 batches).
__global__ __launch_bounds__(448) void k_scan(
    const int* __restrict__ event, const float* __restrict__ dtime,
    const float* __restrict__ EW, const unsigned* __restrict__ wq,
    const float* __restrict__ sc,
    float* __restrict__ zx, int* __restrict__ flags,
    uint2* __restrict__ state) {
  const int x = blockIdx.x;          // 0..63
  const int q = x >> 2;              // quad 0..15
  const int role = x & 3;
  const int tid = threadIdx.x;
  const int row = role * 448 + tid;
  const int b0 = q * QB;

  __shared__ unsigned hh[128][QB];   // h fp16-pairs interleaved: [k2][batch]
  __shared__ int      ev_s[QB][TP2n];
  __shared__ float    dt_s[QB][TP2n];

  const uintx4* wp = reinterpret_cast<const uintx4*>(wq) + (size_t)row * 16;
  const float  sc_r = sc[row];

  for (int i = tid; i < QB * TP2n; i += 448) {
    int m = i >> 10, ii = i & 1023;
    ev_s[m][ii] = event[(size_t)(b0 + m) * TP2n + ii];
    dt_s[m][ii] = dtime[(size_t)(b0 + m) * TP2n + ii];
  }
  for (int i = tid; i < 128 * QB; i += 448)
    reinterpret_cast<unsigned*>(hh)[i] = 0u;
  __syncthreads();

  float c_r[QB], cb_r[QB], ew_pf[QB];
#pragma unroll
  for (int m = 0; m < QB; ++m) {
    c_r[m] = 0.f; cb_r[m] = 0.f;
    ew_pf[m] = EW[(size_t)ev_s[m][0] * H7n + row];
  }

  for (int t = 0; t < Tn; ++t) {
    const int par = t & 1;
    float ewc[QB];
#pragma unroll
    for (int m = 0; m < QB; ++m) {
      ewc[m] = ew_pf[m];
      ew_pf[m] = EW[(size_t)ev_s[m][t + 1] * H7n + row];  // next-step prefetch
    }

    // ---- Phase A: this row x 4 batches (8 acc chains) ----
    float a0[QB], a1[QB];
#pragma unroll
    for (int m = 0; m < QB; ++m) { a0[m] = 0.f; a1[m] = 0.f; }
#pragma unroll
    for (int i = 0; i < 16; ++i) {
      uintx4 ww = wp[i];               // 16 fp8 weights (cols 16i..16i+15)
#pragma unroll
      for (int jj = 0; jj < 4; ++jj) {
        const int j = 4 * i + jj;      // word j: k-pairs (2j, 2j+1)
        unsigned w = ww[jj];
        unsigned f0 = ((w & 0x007f007fu) << 7) | ((w & 0x00800080u) << 8);
        unsigned f1 = ((w & 0x7f007f00u) >> 1) | (w & 0x80008000u);
        uintx4 hA = *reinterpret_cast<const uintx4*>(&hh[2 * j][0]);
        uintx4 hB = *reinterpret_cast<const uintx4*>(&hh[2 * j + 1][0]);
#pragma unroll
        for (int m = 0; m < QB; ++m) {
          a0[m] = fdot2f(u2h(f0), u2h(hA[m]), a0[m]);
          a1[m] = fdot2f(u2h(f1), u2h(hB[m]), a1[m]);
        }
      }
    }

    // ---- exchange: 4 z stores, flags, concurrent polls ----
#pragma unroll
    for (int m = 0; m < QB; ++m) {
      float z = ewc[m] + sc_r * (a0[m] + a1[m]);
      float* zb = zx + ((size_t)(b0 + m) * 2 + par) * H7n;
      __hip_atomic_store(zb + row, z, __ATOMIC_RELAXED,
                         __HIP_MEMORY_SCOPE_AGENT);
    }
    __syncthreads();                 // drains vmcnt: all z stores complete
    if (tid < QB)
      __hip_atomic_store(flags + (b0 + tid) * 16 + role, t + 1,
                         __ATOMIC_RELEASE, __HIP_MEMORY_SCOPE_AGENT);
    if (tid < 4 * QB) {
      int m = tid >> 2, rr = tid & 3;
      // relaxed per-lane spin; lanes exit independently (exec-mask drain)
      while (__hip_atomic_load(flags + (b0 + m) * 16 + rr, __ATOMIC_RELAXED,
                               __HIP_MEMORY_SCOPE_AGENT) <= t) {}
    }
    __builtin_amdgcn_fence(__ATOMIC_ACQUIRE, "agent");
    __syncthreads();

    // ---- Phase B: elementwise recurrence x 4 batches (threads 0..255) ----
    if (tid < Hn) {
      const int j = tid;
#pragma unroll
      for (int m = 0; m < QB; ++m) {
        const float* zb = zx + ((size_t)(b0 + m) * 2 + par) * H7n;
        float zg[7];
#pragma unroll
        for (int g = 0; g < 7; ++g)
          zg[g] = __hip_atomic_load(zb + g * Hn + j, __ATOMIC_RELAXED,
                                    __HIP_MEMORY_SCOPE_AGENT);
        float gi  = sigmf(zg[0]);
        float gf  = sigmf(zg[1]);
        float go  = sigmf(zg[2]);
        float zc  = tanhfast(zg[3]);
        float gib = sigmf(zg[4]);
        float gfb = sigmf(zg[5]);
        float gd  = softplusf(zg[6]);
        float dt  = dt_s[m][t + 1];
        float ci  = gf * c_r[m] + gi * zc;
        float cbi = gfb * cb_r[m] + gib * zc;
        float cn  = cbi + (ci - cbi) * __expf(-gd * dt);
        float hn  = go * tanhfast(cn);
        c_r[m] = cn; cb_r[m] = cbi;
        // write h half into hh[j>>1][m] (two lanes share a dword: byte-enables)
        reinterpret_cast<__half*>(&hh[j >> 1][m])[j & 1] = __float2half(hn);
        if (role == 0) {
          f16x2 p0; p0[0] = (_Float16)ci; p0[1] = (_Float16)cbi;
          f16x2 p1; p1[0] = (_Float16)gd; p1[1] = (_Float16)go;
          uint2 o;
          o.x = __builtin_bit_cast(unsigned, p0);
          o.y = __builtin_bit_cast(unsigned, p1);
          state[((size_t)(b0 + m) * Tn + t) * Hn + j] = o;
        }
      }
    }
    __syncthreads();
  }
}

// ---------------------------------------------------------------------------
// log_lam_tgt, fully parallel: one wave per (b,t). Recomputes h_next from the
// packed state (same formula as sampling with dt = dtime[t+1]).
__global__ __launch_bounds__(256) void k_post(
    const uint2* __restrict__ state, const int* __restrict__ event,
    const float* __restrict__ dtime, const float* __restrict__ Wl,
    float* __restrict__ loglik_sum) {
  const int wid = blockIdx.x * 4 + (threadIdx.x >> 6);  // 0..65471
  const int lane = threadIdx.x & 63;
  const int b = wid / Tn;
  const int t = wid - b * Tn;
  const int tgt = event[b * TP2n + t + 1];
  if (tgt >= Kn) return;                                 // wave-uniform
  const float dtv = dtime[b * TP2n + t + 1];
  const uint2* srow = state + (size_t)wid * Hn;
  uint4 sA = *reinterpret_cast<const uint4*>(srow + lane * 4);
  uint4 sB = *reinterpret_cast<const uint4*>(srow + lane * 4 + 2);
  float4 wl = *reinterpret_cast<const float4*>(Wl + tgt * Hn + lane * 4);
  float h[4];
#pragma unroll
  for (int qq = 0; qq < 4; ++qq) {
    unsigned lo = (qq == 0) ? sA.x : (qq == 1) ? sA.z : (qq == 2) ? sB.x : sB.z;
    unsigned hi = (qq == 0) ? sA.y : (qq == 1) ? sA.w : (qq == 2) ? sB.y : sB.w;
    f16x2 p0 = u2h(lo), p1 = u2h(hi);
    float c = p0[0], cb = p0[1], gd = p1[0], go = p1[1];
    float cs = cb + (c - cb) * __expf(-gd * dtv);
    h[qq] = go * tanhfast(cs);
  }
  float d = h[0] * wl.x + h[1] * wl.y + h[2] * wl.z + h[3] * wl.w;
#pragma unroll
  for (int off = 32; off; off >>= 1) d += __shfl_down(d, off);
  if (lane == 0) atomicAdd(&loglik_sum[b], __logf(softplusf(d) + EPSF));
}

// ---------------------------------------------------------------------------
// Sampling: 1024 blocks (16/batch, 64 samples each) x 128 threads; thread k
// holds Wl row k in registers. Packed-state gather (one uint4/thread),
// next-sample prefetch.
__global__ __launch_bounds__(128) void k_samp(
    const uint2* __restrict__ state, const float* __restrict__ Wl,
    const int* __restrict__ sidx, const float* __restrict__ sdt,
    const float* __restrict__ smask,
    float* __restrict__ lam_acc, float* __restrict__ mask_acc) {
  const int blk = blockIdx.x;
  const int b = blk >> 4;
  const int base = (b << 10) + (blk & 15) * 64;
  const int tid = threadIdx.x;

  f16x2 wr[128];
  {
    const float* wrow = Wl + tid * Hn;
#pragma unroll
    for (int i = 0; i < 128; ++i) {
      f16x2 v; v[0] = (_Float16)wrow[2 * i]; v[1] = (_Float16)wrow[2 * i + 1];
      wr[i] = v;
    }
  }
  __shared__ float4 hy4[Hn / 8];
  __shared__ float  red[2];
  float accl = 0.f, accm = 0.f;

  int   row = sidx[base];
  float dtv = sdt[base];
  float mk  = smask[base];
  uint4 st = *reinterpret_cast<const uint4*>(state + (size_t)row * Hn + 2 * tid);

  for (int s = 0; s < 64; ++s) {
    f16x2 p0 = u2h(st.x), p1 = u2h(st.y);
    f16x2 q0 = u2h(st.z), q1 = u2h(st.w);
    float cs0 = (float)p0[1] + ((float)p0[0] - (float)p0[1]) * __expf(-(float)p1[0] * dtv);
    float cs1 = (float)q0[1] + ((float)q0[0] - (float)q0[1]) * __expf(-(float)q1[0] * dtv);
    f16x2 hp;
    hp[0] = (_Float16)((float)p1[1] * tanhfast(cs0));
    hp[1] = (_Float16)((float)q1[1] * tanhfast(cs1));
    reinterpret_cast<unsigned*>(hy4)[tid] = __builtin_bit_cast(unsigned, hp);

    uint4 st_n = st; float dt_n = dtv, mk_n = mk;
    if (s < 63) {
      int sg = base + s + 1;
      int r2 = sidx[sg];
      dt_n = sdt[sg];
      mk_n = smask[sg];
      st_n = *reinterpret_cast<const uint4*>(state + (size_t)r2 * Hn + 2 * tid);
    }
    __syncthreads();

    float d = 0.f;
#pragma unroll
    for (int q = 0; q < 32; ++q) {
      float4 hq = hy4[q];
      d = fdot2f(wr[4 * q + 0], f2h(hq.x), d);
      d = fdot2f(wr[4 * q + 1], f2h(hq.y), d);
      d = fdot2f(wr[4 * q + 2], f2h(hq.z), d);
      d = fdot2f(wr[4 * q + 3], f2h(hq.w), d);
    }
    float lam = softplusf(d);
#pragma unroll
    for (int off = 32; off; off >>= 1) lam += __shfl_down(lam, off);
    if ((tid & 63) == 0) red[tid >> 6] = lam;
    __syncthreads();
    if (tid == 0) {
      accl += (red[0] + red[1]) * mk;
      accm += mk;
    }
    st = st_n; dtv = dt_n; mk = mk_n;
  }
  if (tid == 0) {
    atomicAdd(&lam_acc[b], accl);
    atomicAdd(&mask_acc[b], accm);
  }
}

// ---------------------------------------------------------------------------
__global__ void k_final(const float* __restrict__ loglik_sum,
                        const float* __restrict__ lam_acc,
                        const float* __restrict__ mask_acc,
                        const float* __restrict__ duration,
                        float* __restrict__ out) {
  int b = threadIdx.x;
  if (b < Bn) out[b] = loglik_sum[b] - (lam_acc[b] / mask_acc[b]) * duration[b];
}

// ---------------------------------------------------------------------------
extern "C" void kernel_launch(void* const* d_in, const int* in_sizes, int n_in,
                              void* d_out, int out_size, void* d_ws, size_t ws_size,
                              hipStream_t stream) {
  const int*   event    = (const int*)d_in[0];
  const float* dtime    = (const float*)d_in[1];
  const float* duration = (const float*)d_in[3];
  const float* sdt      = (const float*)d_in[4];
  const int*   sidx     = (const int*)d_in[5];
  const float* smask    = (const float*)d_in[6];
  const float* Emb      = (const float*)d_in[7];
  const float* W        = (const float*)d_in[8];
  const float* bv       = (const float*)d_in[9];
  const float* Wl       = (const float*)d_in[10];

  char* ws = (char*)d_ws;
  // layout: EW(0.94MB)@0 | wq(448KB)@1MB | acc(768B)+flags(4KB)+sc(7KB)@2MB |
  //         zx(0.92MB)@3MB | packed state(134MB)@4MB
  float*    EW         = (float*)(ws + 0);
  unsigned* wq         = (unsigned*)(ws + (1u << 20));
  float*    lam_acc    = (float*)(ws + (2u << 20));
  float*    mask_acc   = lam_acc + 64;
  float*    loglik_sum = lam_acc + 128;
  int*      flags      = (int*)(ws + (2u << 20) + 4096);
  float*    sc         = (float*)(ws + (2u << 20) + 16384);
  float*    zx         = (float*)(ws + (3u << 20));
  uint2*    state      = (uint2*)(ws + (4u << 20));

  k_ew<<<dim3(NEn), dim3(256), 0, stream>>>(Emb, W, bv, EW);
  k_wq<<<dim3(H7n), dim3(64), 0, stream>>>(W, wq, sc);
  k_init<<<dim3(1), dim3(1024), 0, stream>>>(lam_acc, flags);
  k_scan<<<dim3(Bn / QB * 4), dim3(448), 0, stream>>>(event, dtime, EW, wq,
                                                      sc, zx, flags, state);
  k_post<<<dim3(16368), dim3(256), 0, stream>>>(state, event, dtime, Wl,
                                                loglik_sum);
  k_samp<<<dim3(1024), dim3(128), 0, stream>>>(state, Wl, sidx, sdt, smask,
                                               lam_acc, mask_acc);
  k_final<<<dim3(1), dim3(64), 0, stream>>>(loglik_sum, lam_acc, mask_acc,
                                            duration, (float*)d_out);
}

// Round 11
// 2687.213 us; speedup vs baseline: 3.9884x; 3.9884x over previous
//
#include <hip/hip_runtime.h>
#include <hip/hip_fp16.h>
#include <cstdint>
#include <cstddef>

#define EPSF 2.220446049250313e-16f

// Sizes (fixed by the problem)
#define Bn   64
#define TP2n 1024
#define Tn   1023
#define Hn   256
#define H7n  1792
#define Kn   128
#define NEn  131

typedef _Float16 f16x2 __attribute__((ext_vector_type(2)));
typedef unsigned uintx4 __attribute__((ext_vector_type(4)));

__device__ __forceinline__ f16x2 u2h(unsigned u) { return __builtin_bit_cast(f16x2, u); }
__device__ __forceinline__ f16x2 f2h(float f)    { return __builtin_bit_cast(f16x2, f); }

__device__ __forceinline__ float fdot2f(f16x2 a, f16x2 b, float c) {
#if __has_builtin(__builtin_amdgcn_fdot2)
  return __builtin_amdgcn_fdot2(a, b, c, false);
#else
  return c + (float)a[0] * (float)b[0] + (float)a[1] * (float)b[1];
#endif
}

__device__ __forceinline__ float sigmf(float x) { return 1.f / (1.f + __expf(-x)); }

__device__ __forceinline__ float tanhfast(float x) {
  float t = __expf(2.f * fabsf(x));        // inf-safe: t=inf -> r=1
  float r = 1.f - 2.f / (t + 1.f);
  return copysignf(r, x);
}

__device__ __forceinline__ float softplusf(float x) {
  return fmaxf(x, 0.f) + log1pf(__expf(-fabsf(x)));
}

// fp8-e4m3 pair decode: u32 packed as bytes (b0,b2,b1,b3) -> two f16x2
// (e4m3->f16 exact modulo x2^8, folded into the per-row scale).
__device__ __forceinline__ void dec_dot2(unsigned x, float hp0, float hp1,
                                         float& accA, float& accB) {
  unsigned f0 = ((x & 0x007f007fu) << 7) | ((x & 0x00800080u) << 8);
  unsigned f1 = ((x & 0x7f007f00u) >> 1) | (x & 0x80008000u);
  accA = fdot2f(u2h(f0), f2h(hp0), accA);
  accB = fdot2f(u2h(f1), f2h(hp1), accB);
}

// Row permutation: r' = role*448 + g*64 + u  <->  orig r = g*256 + 64*role + u.
// Role r' block then owns ALL 7 gates of units [64*role, 64*role+64):
// Phase B becomes block-local; only h (512B) crosses blocks.
__device__ __host__ __forceinline__ int orig_row(int rp) {
  int role = rp / 448, i = rp % 448;
  return (i >> 6) * 256 + 64 * role + (i & 63);
}

// ---------------------------------------------------------------------------
// EWp[e][r'] = b[orig(r')] + sum_k Emb[e][k] * W[orig(r')][k]   (k<256)
__global__ void k_ew(const float* __restrict__ Emb, const float* __restrict__ W,
                     const float* __restrict__ bvec, float* __restrict__ EW) {
  int e = blockIdx.x;  // 0..130
  __shared__ float es[Hn];
  for (int k = threadIdx.x; k < Hn; k += blockDim.x) es[k] = Emb[e * Hn + k];
  __syncthreads();
  for (int rp = threadIdx.x; rp < H7n; rp += blockDim.x) {
    int r = orig_row(rp);
    const float* wr = W + (size_t)r * (2 * Hn);
    float acc = bvec[r];
#pragma unroll 4
    for (int k = 0; k < Hn; ++k) acc += es[k] * wr[k];
    EW[e * H7n + rp] = acc;
  }
}

// ---------------------------------------------------------------------------
// Quantize recurrent weights to fp8-e4m3 with per-row scale, PERMUTED rows.
// Word j of row r' = bytes (q[4j],q[4j+2],q[4j+1],q[4j+3]); sc[r'] = s*256.
__global__ __launch_bounds__(64) void k_wq(const float* __restrict__ W,
                                           unsigned* __restrict__ wq,
                                           float* __restrict__ sc) {
  const int rp = blockIdx.x;          // 0..1791 (permuted index)
  const int r  = orig_row(rp);
  const int j  = threadIdx.x;         // 0..63
  const float* wr = W + (size_t)r * 512 + 256;
  float4 wv = *reinterpret_cast<const float4*>(wr + 4 * j);
  float m = fmaxf(fmaxf(fabsf(wv.x), fabsf(wv.y)),
                  fmaxf(fabsf(wv.z), fabsf(wv.w)));
#pragma unroll
  for (int off = 32; off; off >>= 1) m = fmaxf(m, __shfl_xor(m, off));
  float inv_s = (m > 0.f) ? 448.f / m : 0.f;
  float v[4] = {wv.x, wv.y, wv.z, wv.w};
  unsigned b[4];
#pragma unroll
  for (int q = 0; q < 4; ++q) {
    float ay = fabsf(v[q]) * inv_s;     // in [0, 448]
    unsigned byte;
    if (ay < 0.015625f) {               // < 2^-6: denorm m*2^-9 (RNE)
      byte = (unsigned)(int)rintf(ay * 512.f);
    } else {                            // normal: rebias to 7, RNE 3-bit mant
      unsigned ub = __builtin_bit_cast(unsigned, ay);
      unsigned E  = (ub >> 23) & 255u;
      unsigned vv = ((E - 120u) << 23) | (ub & 0x7fffffu);
      byte = (vv + 0x7ffffu + ((vv >> 20) & 1u)) >> 20;
      if (byte > 0x7eu) byte = 0x7eu;
    }
    if (v[q] < 0.f) byte |= 0x80u;
    b[q] = byte;
  }
  wq[(size_t)rp * 64 + j] = b[0] | (b[2] << 8) | (b[1] << 16) | (b[3] << 24);
  if (j == 0) sc[rp] = (m / 448.f) * 256.f;
}

// ---------------------------------------------------------------------------
// Init accumulators and the h-exchange buffer. hx dwords get lsb=1 in both
// halves: first expected tag is 0, so poison (0xAA) / stale data from a
// previous replay can never false-positive the tag poll.
__global__ void k_init(float* __restrict__ acc, unsigned* __restrict__ hx) {
  int i = threadIdx.x;  // 1024 threads
  if (i < 192) acc[i] = 0.f;  // lam_acc[64], mask_acc[64], loglik_sum[64]
  for (int k = i; k < Bn * 256; k += 1024) hx[k] = 0x00010001u;
}

// ---------------------------------------------------------------------------
// Sequential CT-LSTM scan, 4 blocks/batch, 448 threads, 1 permuted row each.
// Rounds 3-10 post-mortem: the 5.6us/step floor was the MALL exchange CHAIN
// (z drain -> flag -> poll -> z reload), not weight bytes. This round the
// row permutation makes Phase B block-local (z lives in LDS); the only
// cross-block datum is h: 32 tagged dwords/role/step. Tags (fp16-lsb =
// (t>>1)&1, parity double buffer) make the payload self-validating: no
// flag, no fence, no vmcnt drain. Reuse-distance 2 is enforced by the
// recurrence's own data dependency (role X can only reach step t+2's
// publish after every role has consumed h(t)).
__global__ __launch_bounds__(448) void k_scan(
    const int* __restrict__ event, const float* __restrict__ dtime,
    const float* __restrict__ EW, const unsigned* __restrict__ wq,
    const float* __restrict__ sc, unsigned* __restrict__ hx,
    uint2* __restrict__ state) {
  const int x = blockIdx.x;
  // co-locate a batch's 4 blocks on one XCD (assumed xcd = blockIdx % 8);
  // correctness does not depend on this mapping.
  const int xcd = x & 7, q = x >> 3;
  const int b = xcd * 8 + (q >> 2);
  const int role = q & 3;
  const int tid = threadIdx.x;
  const int row = role * 448 + tid;     // permuted row index

  __shared__ float    zbuf[448];        // this block's z slice (local!)
  __shared__ unsigned hds[128];         // h fp16-pairs, unit-major (256 halves)
  __shared__ int      ev_s[TP2n];
  __shared__ float    dt_s[TP2n];

  const uintx4* wp = reinterpret_cast<const uintx4*>(wq) + (size_t)row * 16;
  const float  sc_r = sc[row];
  unsigned* hxb = hx + (size_t)b * 256;   // [par][128] dwords

  for (int i = tid; i < TP2n; i += 448) {
    ev_s[i] = event[b * TP2n + i];
    dt_s[i] = dtime[b * TP2n + i];
  }
  if (tid < 128) hds[tid] = 0u;
  __syncthreads();

  float c_r = 0.f, cb_r = 0.f;          // unit state (threads 0..63)
  const int j_u = 64 * role + tid;      // this thread's unit (tid<64)
  float ew_pf = EW[(size_t)ev_s[0] * H7n + row];

  for (int t = 0; t < Tn; ++t) {
    float ewc = ew_pf;
    ew_pf = EW[(size_t)ev_s[t + 1] * H7n + row];  // next-step prefetch

    // ---- Phase A: z for this row (fp8 weights, h broadcast from LDS) ----
    float a0 = 0.f, a1 = 0.f, a2 = 0.f, a3 = 0.f;
    const float4* h4 = reinterpret_cast<const float4*>(hds);
#pragma unroll
    for (int i = 0; i < 16; ++i) {
      uintx4 ww = wp[i];               // 16 fp8 weights (cols 16i..16i+15)
      float4 hA = h4[2 * i];
      float4 hB = h4[2 * i + 1];
      dec_dot2(ww[0], hA.x, hA.y, a0, a1);
      dec_dot2(ww[1], hA.z, hA.w, a2, a3);
      dec_dot2(ww[2], hB.x, hB.y, a0, a1);
      dec_dot2(ww[3], hB.z, hB.w, a2, a3);
    }
    zbuf[tid] = ewc + sc_r * ((a0 + a1) + (a2 + a3));
    __syncthreads();

    // ---- Phase B: block-local recurrence for 64 owned units (tid<64) ----
    if (tid < 64) {
      float gi  = sigmf(zbuf[tid]);
      float gf  = sigmf(zbuf[64 + tid]);
      float go  = sigmf(zbuf[128 + tid]);
      float zc  = tanhfast(zbuf[192 + tid]);
      float gib = sigmf(zbuf[256 + tid]);
      float gfb = sigmf(zbuf[320 + tid]);
      float gd  = softplusf(zbuf[384 + tid]);
      float dt  = dt_s[t + 1];
      float ci  = gf * c_r + gi * zc;
      float cbi = gfb * cb_r + gib * zc;
      float cn  = cbi + (ci - cbi) * __expf(-gd * dt);
      float hn  = go * tanhfast(cn);
      c_r = cn; cb_r = cbi;
      reinterpret_cast<__half*>(hds)[j_u] = __float2half(hn);
      f16x2 p0; p0[0] = (_Float16)ci; p0[1] = (_Float16)cbi;
      f16x2 p1; p1[0] = (_Float16)gd; p1[1] = (_Float16)go;
      uint2 o;
      o.x = __builtin_bit_cast(unsigned, p0);
      o.y = __builtin_bit_cast(unsigned, p1);
      state[((size_t)b * Tn + t) * Hn + j_u] = o;
    }
    __syncthreads();

    // ---- h exchange: publish own 32 tagged dwords; poll remote 96 ----
    if (t < Tn - 1) {
      const unsigned par  = (unsigned)(t & 1);
      const unsigned tau  = (unsigned)((t >> 1) & 1);
      const unsigned tagw = tau * 0x00010001u;
      if (tid < 32) {
        unsigned d = hds[32 * role + tid];
        __hip_atomic_store(hxb + par * 128 + 32 * role + tid,
                           (d & 0xFFFEFFFEu) | tagw,
                           __ATOMIC_RELAXED, __HIP_MEMORY_SCOPE_AGENT);
      } else if (tid >= 64 && tid < 160) {
        int k  = tid - 64;                       // 0..95
        int rr = (role + 1 + (k >> 5)) & 3;      // the 3 other roles
        int m  = 32 * rr + (k & 31);
        unsigned v;
        do {
          v = __hip_atomic_load(hxb + par * 128 + m, __ATOMIC_RELAXED,
                                __HIP_MEMORY_SCOPE_AGENT);
        } while ((v & 1u) != tau);
        hds[m] = v;                              // lsb-tag noise: 2^-11, ok
      }
      __syncthreads();
    }
  }
}

// ---------------------------------------------------------------------------
// log_lam_tgt, fully parallel: one wave per (b,t). Recomputes h_next from the
// packed state (same formula as sampling with dt = dtime[t+1]).
__global__ __launch_bounds__(256) void k_post(
    const uint2* __restrict__ state, const int* __restrict__ event,
    const float* __restrict__ dtime, const float* __restrict__ Wl,
    float* __restrict__ loglik_sum) {
  const int wid = blockIdx.x * 4 + (threadIdx.x >> 6);  // 0..65471
  const int lane = threadIdx.x & 63;
  const int b = wid / Tn;
  const int t = wid - b * Tn;
  const int tgt = event[b * TP2n + t + 1];
  if (tgt >= Kn) return;                                 // wave-uniform
  const float dtv = dtime[b * TP2n + t + 1];
  const uint2* srow = state + (size_t)wid * Hn;
  uint4 sA = *reinterpret_cast<const uint4*>(srow + lane * 4);
  uint4 sB = *reinterpret_cast<const uint4*>(srow + lane * 4 + 2);
  float4 wl = *reinterpret_cast<const float4*>(Wl + tgt * Hn + lane * 4);
  float h[4];
#pragma unroll
  for (int qq = 0; qq < 4; ++qq) {
    unsigned lo = (qq == 0) ? sA.x : (qq == 1) ? sA.z : (qq == 2) ? sB.x : sB.z;
    unsigned hi = (qq == 0) ? sA.y : (qq == 1) ? sA.w : (qq == 2) ? sB.y : sB.w;
    f16x2 p0 = u2h(lo), p1 = u2h(hi);
    float c = p0[0], cb = p0[1], gd = p1[0], go = p1[1];
    float cs = cb + (c - cb) * __expf(-gd * dtv);
    h[qq] = go * tanhfast(cs);
  }
  float d = h[0] * wl.x + h[1] * wl.y + h[2] * wl.z + h[3] * wl.w;
#pragma unroll
  for (int off = 32; off; off >>= 1) d += __shfl_down(d, off);
  if (lane == 0) atomicAdd(&loglik_sum[b], __logf(softplusf(d) + EPSF));
}

// ---------------------------------------------------------------------------
// Sampling: 1024 blocks (16/batch, 64 samples each) x 128 threads; thread k
// holds Wl row k in registers. Packed-state gather (one uint4/thread),
// next-sample prefetch.
__global__ __launch_bounds__(128) void k_samp(
    const uint2* __restrict__ state, const float* __restrict__ Wl,
    const int* __restrict__ sidx, const float* __restrict__ sdt,
    const float* __restrict__ smask,
    float* __restrict__ lam_acc, float* __restrict__ mask_acc) {
  const int blk = blockIdx.x;
  const int b = blk >> 4;
  const int base = (b << 10) + (blk & 15) * 64;
  const int tid = threadIdx.x;

  f16x2 wr[128];
  {
    const float* wrow = Wl + tid * Hn;
#pragma unroll
    for (int i = 0; i < 128; ++i) {
      f16x2 v; v[0] = (_Float16)wrow[2 * i]; v[1] = (_Float16)wrow[2 * i + 1];
      wr[i] = v;
    }
  }
  __shared__ float4 hy4[Hn / 8];
  __shared__ float  red[2];
  float accl = 0.f, accm = 0.f;

  int   row = sidx[base];
  float dtv = sdt[base];
  float mk  = smask[base];
  uint4 st = *reinterpret_cast<const uint4*>(state + (size_t)row * Hn + 2 * tid);

  for (int s = 0; s < 64; ++s) {
    f16x2 p0 = u2h(st.x), p1 = u2h(st.y);
    f16x2 q0 = u2h(st.z), q1 = u2h(st.w);
    float cs0 = (float)p0[1] + ((float)p0[0] - (float)p0[1]) * __expf(-(float)p1[0] * dtv);
    float cs1 = (float)q0[1] + ((float)q0[0] - (float)q0[1]) * __expf(-(float)q1[0] * dtv);
    f16x2 hp;
    hp[0] = (_Float16)((float)p1[1] * tanhfast(cs0));
    hp[1] = (_Float16)((float)q1[1] * tanhfast(cs1));
    reinterpret_cast<unsigned*>(hy4)[tid] = __builtin_bit_cast(unsigned, hp);

    uint4 st_n = st; float dt_n = dtv, mk_n = mk;
    if (s < 63) {
      int sg = base + s + 1;
      int r2 = sidx[sg];
      dt_n = sdt[sg];
      mk_n = smask[sg];
      st_n = *reinterpret_cast<const uint4*>(state + (size_t)r2 * Hn + 2 * tid);
    }
    __syncthreads();

    float d = 0.f;
#pragma unroll
    for (int q = 0; q < 32; ++q) {
      float4 hq = hy4[q];
      d = fdot2f(wr[4 * q + 0], f2h(hq.x), d);
      d = fdot2f(wr[4 * q + 1], f2h(hq.y), d);
      d = fdot2f(wr[4 * q + 2], f2h(hq.z), d);
      d = fdot2f(wr[4 * q + 3], f2h(hq.w), d);
    }
    float lam = softplusf(d);
#pragma unroll
    for (int off = 32; off; off >>= 1) lam += __shfl_down(lam, off);
    if ((tid & 63) == 0) red[tid >> 6] = lam;
    __syncthreads();
    if (tid == 0) {
      accl += (red[0] + red[1]) * mk;
      accm += mk;
    }
    st = st_n; dtv = dt_n; mk = mk_n;
  }
  if (tid == 0) {
    atomicAdd(&lam_acc[b], accl);
    atomicAdd(&mask_acc[b], accm);
  }
}

// ---------------------------------------------------------------------------
__global__ void k_final(const float* __restrict__ loglik_sum,
                        const float* __restrict__ lam_acc,
                        const float* __restrict__ mask_acc,
                        const float* __restrict__ duration,
                        float* __restrict__ out) {
  int b = threadIdx.x;
  if (b < Bn) out[b] = loglik_sum[b] - (lam_acc[b] / mask_acc[b]) * duration[b];
}

// ---------------------------------------------------------------------------
extern "C" void kernel_launch(void* const* d_in, const int* in_sizes, int n_in,
                              void* d_out, int out_size, void* d_ws, size_t ws_size,
                              hipStream_t stream) {
  const int*   event    = (const int*)d_in[0];
  const float* dtime    = (const float*)d_in[1];
  const float* duration = (const float*)d_in[3];
  const float* sdt      = (const float*)d_in[4];
  const int*   sidx     = (const int*)d_in[5];
  const float* smask    = (const float*)d_in[6];
  const float* Emb      = (const float*)d_in[7];
  const float* W        = (const float*)d_in[8];
  const float* bv       = (const float*)d_in[9];
  const float* Wl       = (const float*)d_in[10];

  char* ws = (char*)d_ws;
  // layout: EWp(0.94MB)@0 | wq(448KB)@1MB | acc(768B)@2MB | hx(64KB)@2MB+8KB |
  //         sc(7KB)@2MB+80KB | packed state(134MB)@4MB
  float*    EW         = (float*)(ws + 0);
  unsigned* wq         = (unsigned*)(ws + (1u << 20));
  float*    lam_acc    = (float*)(ws + (2u << 20));
  float*    mask_acc   = lam_acc + 64;
  float*    loglik_sum = lam_acc + 128;
  unsigned* hx         = (unsigned*)(ws + (2u << 20) + 8192);
  float*    sc         = (float*)(ws + (2u << 20) + 81920);
  uint2*    state      = (uint2*)(ws + (4u << 20));

  k_ew<<<dim3(NEn), dim3(256), 0, stream>>>(Emb, W, bv, EW);
  k_wq<<<dim3(H7n), dim3(64), 0, stream>>>(W, wq, sc);
  k_init<<<dim3(1), dim3(1024), 0, stream>>>(lam_acc, hx);
  k_scan<<<dim3(256), dim3(448), 0, stream>>>(event, dtime, EW, wq, sc, hx,
                                              state);
  k_post<<<dim3(16368), dim3(256), 0, stream>>>(state, event, dtime, Wl,
                                                loglik_sum);
  k_samp<<<dim3(1024), dim3(128), 0, stream>>>(state, Wl, sidx, sdt, smask,
                                               lam_acc, mask_acc);
  k_final<<<dim3(1), dim3(64), 0, stream>>>(loglik_sum, lam_acc, mask_acc,
                                            duration, (float*)d_out);
}